// Round 4
// baseline (153.695 us; speedup 1.0000x reference)
//
#include <hip/hip_runtime.h>

// out[b][h][w][k] = (|h-r[b][k]|<=5 && |w-c[b][k]|<=5) ? 1.0f : 0.0f
// out shape (256,128,64,18) fp32 = 151 MB -> pure write-BW-bound.
// Block = 9216 consecutive floats = 512 pixels = 8 rows of one batch image.
// Value of pixel's k-th float = bit k of (rowmask[h] & colmask[w]).

constexpr int KP = 18;
constexpr int AH = 5;
constexpr int AW = 5;

typedef float vfloat4 __attribute__((ext_vector_type(4)));

__global__ __launch_bounds__(256) void posemap_kernel(const int* __restrict__ x,
                                                      float* __restrict__ out) {
    const int blk = blockIdx.x;
    const int b   = blk >> 4;           // 16 blocks per batch
    const int h0  = (blk & 15) << 3;    // first of 8 rows this block covers

    __shared__ unsigned rowmask[8];
    __shared__ unsigned colmask[64];

    const int t = threadIdx.x;
    const int* __restrict__ xb = x + b * (KP * 2);  // uniform per block

    if (t < 8) {
        const int h = h0 + t;
        unsigned m = 0;
        #pragma unroll
        for (int k = 0; k < KP; ++k) {
            const int r = xb[2 * k];
            m |= (unsigned)((unsigned)(h - r + AH) <= (unsigned)(2 * AH)) << k;
        }
        rowmask[t] = m;
    } else if (t >= 64 && t < 128) {
        const int w = t - 64;
        unsigned m = 0;
        #pragma unroll
        for (int k = 0; k < KP; ++k) {
            const int c = xb[2 * k + 1];
            m |= (unsigned)((unsigned)(w - c + AW) <= (unsigned)(2 * AW)) << k;
        }
        colmask[w] = m;
    }
    __syncthreads();

    float* __restrict__ obase = out + (size_t)blk * 9216;

    #pragma unroll
    for (int j = 0; j < 9; ++j) {
        const int q  = j * 256 + t;        // float4 index within block, 0..2303
        const int m  = q * 4;              // element offset, 0..9212
        const int pl = (int)((unsigned)m / 18u);   // local pixel 0..511
        const int k0 = m - pl * 18;                // first k of this float4

        const int pl2 = (pl + 1) & 511;    // straddle pixel (wrap unused: last f4 has k0=14)
        const unsigned m1 = rowmask[pl  >> 6] & colmask[pl  & 63];
        const unsigned m2 = rowmask[pl2 >> 6] & colmask[pl2 & 63];
        const unsigned long long bits =
            (unsigned long long)m1 | ((unsigned long long)m2 << KP);

        vfloat4 v;
        v.x = (float)((bits >> (k0 + 0)) & 1ull);
        v.y = (float)((bits >> (k0 + 1)) & 1ull);
        v.z = (float)((bits >> (k0 + 2)) & 1ull);
        v.w = (float)((bits >> (k0 + 3)) & 1ull);

        // Streaming store: bypass cache allocation (nt flag), coalesced 1 KiB/wave/instr.
        __builtin_nontemporal_store(v, reinterpret_cast<vfloat4*>(obase + m));
    }
}

extern "C" void kernel_launch(void* const* d_in, const int* in_sizes, int n_in,
                              void* d_out, int out_size, void* d_ws, size_t ws_size,
                              hipStream_t stream) {
    const int* x = (const int*)d_in[0];
    float* out   = (float*)d_out;
    posemap_kernel<<<4096, 256, 0, stream>>>(x, out);
}

// Round 5
// 152.014 us; speedup vs baseline: 1.0111x; 1.0111x over previous
//
#include <hip/hip_runtime.h>

// out[b][h][w][k] = (|h-r[b][k]|<=5 && |w-c[b][k]|<=5) ? 1.0f : 0.0f
// out shape (256,128,64,18) fp32 = 151 MB -> pure write-BW-bound.
// Block = quarter image: 32 rows x 64 cols x 18 k = 36,864 consecutive floats.
// Grid = 256 batches x 4 = 1024 blocks; 36 float4 stores per thread.
// Value of pixel's k-th float = bit k of (rowmask[h] & colmask[w]).

constexpr int KP = 18;
constexpr int AH = 5;
constexpr int AW = 5;

__global__ __launch_bounds__(256) void posemap_kernel(const int* __restrict__ x,
                                                      float* __restrict__ out) {
    const int blk = blockIdx.x;
    const int b   = blk >> 2;           // 4 blocks per batch image
    const int h0  = (blk & 3) << 5;     // first of 32 rows this block covers

    __shared__ unsigned rowmask[32];
    __shared__ unsigned colmask[64];

    const int t = threadIdx.x;
    const int* __restrict__ xb = x + b * (KP * 2);  // uniform per block -> s_loads

    if (t < 32) {
        const int h = h0 + t;
        unsigned m = 0;
        #pragma unroll
        for (int k = 0; k < KP; ++k) {
            const int r = xb[2 * k];
            m |= (unsigned)((unsigned)(h - r + AH) <= (unsigned)(2 * AH)) << k;
        }
        rowmask[t] = m;
    } else if (t >= 64 && t < 128) {
        const int w = t - 64;
        unsigned m = 0;
        #pragma unroll
        for (int k = 0; k < KP; ++k) {
            const int c = xb[2 * k + 1];
            m |= (unsigned)((unsigned)(w - c + AW) <= (unsigned)(2 * AW)) << k;
        }
        colmask[w] = m;
    }
    __syncthreads();

    float* __restrict__ obase = out + (size_t)blk * 36864;

    #pragma unroll
    for (int j = 0; j < 36; ++j) {
        const int q  = j * 256 + t;        // float4 index within block, 0..9215
        const int m  = q * 4;              // element offset, 0..36860
        const int pl = (int)((unsigned)m / 18u);   // local pixel 0..2047 (mulhi magic)
        const int k0 = m - pl * 18;                // first k of this float4

        const int pl2 = (pl + 1) & 2047;   // straddle pixel (wrap unused: last f4 has k0=14)
        const unsigned m1 = rowmask[pl  >> 6] & colmask[pl  & 63];
        const unsigned m2 = rowmask[pl2 >> 6] & colmask[pl2 & 63];
        const unsigned long long bits =
            (unsigned long long)m1 | ((unsigned long long)m2 << KP);

        float4 v;
        v.x = (float)((bits >> (k0 + 0)) & 1ull);
        v.y = (float)((bits >> (k0 + 1)) & 1ull);
        v.z = (float)((bits >> (k0 + 2)) & 1ull);
        v.w = (float)((bits >> (k0 + 3)) & 1ull);

        *reinterpret_cast<float4*>(obase + m) = v;   // coalesced: wave writes 1 KiB contiguous
    }
}

extern "C" void kernel_launch(void* const* d_in, const int* in_sizes, int n_in,
                              void* d_out, int out_size, void* d_ws, size_t ws_size,
                              hipStream_t stream) {
    const int* x = (const int*)d_in[0];
    float* out   = (float*)d_out;
    // 37,748,736 floats / 36,864 per block = 1024 blocks
    posemap_kernel<<<1024, 256, 0, stream>>>(x, out);
}